// Round 2
// baseline (2517.423 us; speedup 1.0000x reference)
//
#include <hip/hip_runtime.h>
#include <hip/hip_bf16.h>

#define H 128
#define FOURH 512
#define BATCH 64
#define SEQ 2048
#define TC SEQ
#define RH 1024   // h1p ring depth (steps)
#define RG 128    // G1 ring depth (steps)
#define CCH 32    // stage-C chunk (steps)

typedef _Float16 half8 __attribute__((ext_vector_type(8)));
typedef float f32x4 __attribute__((ext_vector_type(4)));

// ---------------- prep: transpose Wih0 -> [K][512], sum biases, zero flags ----
__global__ void prep_kernel(const float* __restrict__ Wih0,
                            const float* __restrict__ bih0, const float* __restrict__ bhh0,
                            const float* __restrict__ bih1, const float* __restrict__ bhh1,
                            float* __restrict__ Wt0,
                            float* __restrict__ b0, float* __restrict__ b1,
                            int* __restrict__ flags) {
    int id = blockIdx.x * 256 + threadIdx.x;
    const int N0 = 256 * 512;
    if (id < N0) {
        int k = id >> 9, n = id & 511;
        Wt0[id] = Wih0[n * 256 + k];
    } else if (id < N0 + 512) {
        int i = id - N0;
        b0[i] = bih0[i] + bhh0[i];
    } else if (id < N0 + 1024) {
        int i = id - (N0 + 512);
        b1[i] = bih1[i] + bhh1[i];
    } else if (id < N0 + 1024 + 24) {
        flags[id - (N0 + 1024)] = 0;
    }
}

// ---------------- fp32 GEMM: G[m][n] = sum_k A[row(m)][k]*Bt[k][n] + bias[n] --
#define BM 128
#define BN 128
#define BK 32

__global__ __launch_bounds__(256) void gemm_bias_kernel(
    const float* __restrict__ A, int lda, int rowsPerBatch, int t0,
    const float* __restrict__ Bt, const float* __restrict__ bias,
    float* __restrict__ G, int K, int tcShift)
{
    __shared__ float As[BK][BM + 4];
    __shared__ float Bs[BK][BN];

    const int tid = threadIdx.x;
    const int m0 = blockIdx.y * BM;
    const int n0 = blockIdx.x * BN;
    const int tm = tid >> 4;
    const int tn = tid & 15;
    const int tcMask = (1 << tcShift) - 1;

    const float* aptr[4];
    int ar[4], aq[4];
#pragma unroll
    for (int l = 0; l < 4; ++l) {
        int fidx = tid + l * 256;
        int r = fidx >> 3, q = fidx & 7;
        ar[l] = r; aq[l] = q;
        int m = m0 + r;
        int bi = m >> tcShift;
        int tl = m & tcMask;
        aptr[l] = A + ((size_t)bi * rowsPerBatch + t0 + tl) * lda + q * 4;
    }
    int bkk[4], bq[4];
#pragma unroll
    for (int l = 0; l < 4; ++l) {
        int fidx = tid + l * 256;
        bkk[l] = fidx >> 5; bq[l] = fidx & 31;
    }

    float acc[2][2][4][4];
#pragma unroll
    for (int ri = 0; ri < 2; ++ri)
#pragma unroll
        for (int ci = 0; ci < 2; ++ci)
#pragma unroll
            for (int i = 0; i < 4; ++i)
#pragma unroll
                for (int j = 0; j < 4; ++j) acc[ri][ci][i][j] = 0.f;

    for (int k0 = 0; k0 < K; k0 += BK) {
        __syncthreads();
#pragma unroll
        for (int l = 0; l < 4; ++l) {
            float4 v = *(const float4*)(aptr[l] + k0);
            As[aq[l] * 4 + 0][ar[l]] = v.x;
            As[aq[l] * 4 + 1][ar[l]] = v.y;
            As[aq[l] * 4 + 2][ar[l]] = v.z;
            As[aq[l] * 4 + 3][ar[l]] = v.w;
        }
#pragma unroll
        for (int l = 0; l < 4; ++l) {
            float4 v = *(const float4*)(Bt + (size_t)(k0 + bkk[l]) * FOURH + n0 + bq[l] * 4);
            *(float4*)&Bs[bkk[l]][bq[l] * 4] = v;
        }
        __syncthreads();
#pragma unroll
        for (int kk = 0; kk < BK; ++kk) {
            float a[8], bb[8];
            *(float4*)&a[0] = *(const float4*)&As[kk][tm * 4];
            *(float4*)&a[4] = *(const float4*)&As[kk][64 + tm * 4];
            *(float4*)&bb[0] = *(const float4*)&Bs[kk][tn * 4];
            *(float4*)&bb[4] = *(const float4*)&Bs[kk][64 + tn * 4];
#pragma unroll
            for (int ri = 0; ri < 2; ++ri)
#pragma unroll
                for (int i = 0; i < 4; ++i)
#pragma unroll
                    for (int ci = 0; ci < 2; ++ci)
#pragma unroll
                        for (int j = 0; j < 4; ++j)
                            acc[ri][ci][i][j] = fmaf(a[ri * 4 + i], bb[ci * 4 + j], acc[ri][ci][i][j]);
        }
    }

    float4 bv0 = *(const float4*)&bias[n0 + tn * 4];
    float4 bv1 = *(const float4*)&bias[n0 + 64 + tn * 4];
#pragma unroll
    for (int ri = 0; ri < 2; ++ri)
#pragma unroll
        for (int i = 0; i < 4; ++i) {
            int m = m0 + ri * 64 + tm * 4 + i;
            float* gp = G + (size_t)m * FOURH + n0;
            float4 o0 = make_float4(acc[ri][0][i][0] + bv0.x, acc[ri][0][i][1] + bv0.y,
                                    acc[ri][0][i][2] + bv0.z, acc[ri][0][i][3] + bv0.w);
            float4 o1 = make_float4(acc[ri][1][i][0] + bv1.x, acc[ri][1][i][1] + bv1.y,
                                    acc[ri][1][i][2] + bv1.z, acc[ri][1][i][3] + bv1.w);
            *(float4*)(gp + tn * 4) = o0;
            *(float4*)(gp + 64 + tn * 4) = o1;
        }
}

// ---------------- fused 3-stage MFMA LSTM pipeline ----------------
__device__ __forceinline__ float sigmoid_f(float x) {
    return __builtin_amdgcn_rcpf(1.f + __expf(-x));
}
__device__ __forceinline__ float tanh_f(float x) {
    return 1.f - 2.f * __builtin_amdgcn_rcpf(__expf(2.f * x) + 1.f);
}

// Light barrier: LDS handoff only. Global loads/stores stay in flight across it.
#define LDS_BARRIER()                                                \
    do {                                                             \
        asm volatile("s_waitcnt lgkmcnt(0)" ::: "memory");           \
        __builtin_amdgcn_s_barrier();                                \
        __builtin_amdgcn_sched_barrier(0);                           \
    } while (0)

// 24 blocks x 512 threads, per batch-group g (8 batches each):
//   blocks 0-7   (producer): layer-0 scan. Reads G0=xW+b (precomputed), writes
//                h1 into the h1p ring (RH=1024 steps), publishes prodF every 16.
//   blocks 16-23 (stage C):  bulk GEMM G1[t]=h1_t@Wih1^T+b1 in 32-step chunks
//                into the G1 ring (RG=128 steps, f32, L2-resident), gated on
//                prodF (data) and consF (ring space). 3.5x faster than consumed.
//   blocks 8-15  (consumer): layer-1 recurrent-only scan (16 MFMA/step, same
//                cost as producer). Reads G1 ring, publishes consF every 16.
// Deadlock-free: every wait targets a strictly lagged index of its peer stage.
__global__ __launch_bounds__(512, 2) void lstm_fused_kernel(
    const float* __restrict__ G,      // [64][T][512] layer-0 gate pre-activations
    const float* __restrict__ Whh0,   // [512][128]
    const float* __restrict__ Wih1,   // [512][128]
    const float* __restrict__ Whh1,   // [512][128]
    const float* __restrict__ b1,     // [512] summed layer-1 biases
    _Float16* __restrict__ h1p,       // [RH][64][128] fp16 layer-0 hidden ring
    float* __restrict__ G1r,          // [RG][64][512] f32 layer-1 gate-input ring
    float* __restrict__ out,          // [64][T][128] fp32 layer-1 hidden
    int* __restrict__ flags)          // [24]: prodF[8], cF[8], consF[8]
{
    const int tid = threadIdx.x;
    const int w  = tid >> 6;
    const int l  = tid & 63;
    const int li = l & 15;
    const int q  = l >> 4;
    const int u  = 16 * w + li;                 // owned hidden unit (C col)
    const int b0 = q * 2;                       // local batch for C-row r=0
    const int ab = ((li >> 2) * 2) + (li & 1);  // A-row -> local batch (dup map)

    int* prodF = flags;
    int* cF    = flags + 8;
    int* consF = flags + 16;

    __shared__ _Float16 hbuf[2][8][136];        // recurrent h, fp16, dbuf
    __shared__ float houtb[8][8][132];          // consumer output staging

    if (blockIdx.x < 8) {
        // ================= producer: layer 0 =================
        const int g = blockIdx.x;

        half8 Bf[4][4];
#pragma unroll
        for (int tl = 0; tl < 4; ++tl)
#pragma unroll
            for (int kf = 0; kf < 4; ++kf) {
                const float* wp = Whh0 + (size_t)(tl * 128 + u) * H + kf * 32 + q * 8;
                float4 v0 = *(const float4*)wp;
                float4 v1 = *(const float4*)(wp + 4);
                half8 b;
                b[0] = (_Float16)v0.x; b[1] = (_Float16)v0.y;
                b[2] = (_Float16)v0.z; b[3] = (_Float16)v0.w;
                b[4] = (_Float16)v1.x; b[5] = (_Float16)v1.y;
                b[6] = (_Float16)v1.z; b[7] = (_Float16)v1.w;
                Bf[tl][kf] = b;
            }

        float c0 = 0.f, c1 = 0.f, h0 = 0.f, h1v = 0.f;
        hbuf[0][b0][u]     = (_Float16)0.f;
        hbuf[0][b0 + 1][u] = (_Float16)0.f;

        const float* gb = G + (size_t)(8 * g) * TC * FOURH;
        const int voff0 = b0 * TC * FOURH + u;
        const int voff1 = (b0 + 1) * TC * FOURH + u;

        // depth-4 register prefetch of G0 (static register sets; self-reload)
        float G0[8], G1[8], G2[8], G3[8];
        const float* gld = gb;
#pragma unroll
        for (int tl = 0; tl < 4; ++tl) {
            G0[tl * 2 + 0] = gld[voff0 + tl * H];
            G0[tl * 2 + 1] = gld[voff1 + tl * H];
        }
        gld += FOURH;
#pragma unroll
        for (int tl = 0; tl < 4; ++tl) {
            G1[tl * 2 + 0] = gld[voff0 + tl * H];
            G1[tl * 2 + 1] = gld[voff1 + tl * H];
        }
        gld += FOURH;
#pragma unroll
        for (int tl = 0; tl < 4; ++tl) {
            G2[tl * 2 + 0] = gld[voff0 + tl * H];
            G2[tl * 2 + 1] = gld[voff1 + tl * H];
        }
        gld += FOURH;
#pragma unroll
        for (int tl = 0; tl < 4; ++tl) {
            G3[tl * 2 + 0] = gld[voff0 + tl * H];
            G3[tl * 2 + 1] = gld[voff1 + tl * H];
        }
        gld += FOURH;   // now points at t=4

        _Float16* php = h1p + (size_t)(8 * g + b0) * H + u;   // slot 0
        __syncthreads();

#define P_STEP(PB, GR)                                                            \
    {                                                                             \
        half8 Afr[4];                                                             \
        _Pragma("unroll")                                                         \
        for (int kf = 0; kf < 4; ++kf)                                            \
            Afr[kf] = *(const half8*)&hbuf[PB][ab][kf * 32 + q * 8];              \
        f32x4 acc[4];                                                             \
        _Pragma("unroll")                                                         \
        for (int tl = 0; tl < 4; ++tl) {                                          \
            acc[tl][0] = GR[tl * 2 + 0]; acc[tl][1] = GR[tl * 2 + 1];             \
            acc[tl][2] = 0.f;            acc[tl][3] = 0.f;                        \
        }                                                                         \
        _Pragma("unroll")                                                         \
        for (int tl = 0; tl < 4; ++tl) {                                          \
            GR[tl * 2 + 0] = gld[voff0 + tl * H];                                 \
            GR[tl * 2 + 1] = gld[voff1 + tl * H];                                 \
        }                                                                         \
        gld += FOURH;                                                             \
        _Pragma("unroll")                                                         \
        for (int kf = 0; kf < 4; ++kf)                                            \
            _Pragma("unroll")                                                     \
            for (int tl = 0; tl < 4; ++tl)                                        \
                acc[tl] = __builtin_amdgcn_mfma_f32_16x16x32_f16(Afr[kf], Bf[tl][kf], acc[tl], 0, 0, 0); \
        {                                                                         \
            float ig = sigmoid_f(acc[0][0]);                                      \
            float fg = sigmoid_f(acc[1][0]);                                      \
            float gg = tanh_f(acc[2][0]);                                         \
            float og = sigmoid_f(acc[3][0]);                                      \
            c0 = fmaf(fg, c0, ig * gg);                                           \
            h0 = og * tanh_f(c0);                                                 \
            float ig1 = sigmoid_f(acc[0][1]);                                     \
            float fg1 = sigmoid_f(acc[1][1]);                                     \
            float gg1 = tanh_f(acc[2][1]);                                        \
            float og1 = sigmoid_f(acc[3][1]);                                     \
            c1 = fmaf(fg1, c1, ig1 * gg1);                                        \
            h1v = og1 * tanh_f(c1);                                               \
        }                                                                         \
        hbuf[PB ^ 1][b0][u]     = (_Float16)h0;                                   \
        hbuf[PB ^ 1][b0 + 1][u] = (_Float16)h1v;                                  \
        php[0]   = (_Float16)h0;                                                  \
        php[128] = (_Float16)h1v;                                                 \
        php += BATCH * H;                                                         \
        LDS_BARRIER();                                                            \
    }

        for (int s4 = 0; s4 < TC; s4 += 4) {
            if ((s4 & 15) == 0 && s4) {
                // reset ring pointer; wait for stage C to vacate slots we overwrite
                php = h1p + (size_t)(s4 & (RH - 1)) * (BATCH * H)
                    + (size_t)(8 * g + b0) * H + u;
                if (s4 >= RH) {
                    if (tid == 0) {
                        while (__hip_atomic_load(&cF[g], __ATOMIC_ACQUIRE,
                                                 __HIP_MEMORY_SCOPE_AGENT) < s4 - (RH - CCH))
                            __builtin_amdgcn_s_sleep(2);
                    }
                    __syncthreads();
                }
            }
            P_STEP(0, G0)
            P_STEP(1, G1)
            P_STEP(0, G2)
            P_STEP(1, G3)
            if ((s4 & 15) == 12) {
                __threadfence();            // drain + make h1p stores device-visible
                __syncthreads();            // all waves fenced before flag
                if (tid == 0)
                    __hip_atomic_store(&prodF[g], s4 + 4, __ATOMIC_RELEASE,
                                       __HIP_MEMORY_SCOPE_AGENT);
            }
        }
#undef P_STEP
    } else if (blockIdx.x < 16) {
        // ================= consumer: layer 1 (recurrent only) =================
        const int g = blockIdx.x - 8;

        half8 Bf[4][4];   // Whh1 fragments only
#pragma unroll
        for (int tl = 0; tl < 4; ++tl)
#pragma unroll
            for (int kf = 0; kf < 4; ++kf) {
                const float* wp = Whh1 + (size_t)(tl * 128 + u) * H + kf * 32 + q * 8;
                float4 v0 = *(const float4*)wp;
                float4 v1 = *(const float4*)(wp + 4);
                half8 b;
                b[0] = (_Float16)v0.x; b[1] = (_Float16)v0.y;
                b[2] = (_Float16)v0.z; b[3] = (_Float16)v0.w;
                b[4] = (_Float16)v1.x; b[5] = (_Float16)v1.y;
                b[6] = (_Float16)v1.z; b[7] = (_Float16)v1.w;
                Bf[tl][kf] = b;
            }

        float c0 = 0.f, c1 = 0.f, h0, h1v;
        hbuf[0][b0][u]     = (_Float16)0.f;
        hbuf[0][b0 + 1][u] = (_Float16)0.f;

        const int goff0 = (8 * g + b0) * FOURH + u;
        const int goff1 = goff0 + FOURH;
        float* houtBase = out + (size_t)(8 * g) * SEQ * H;

        // initial acquire: first stage-C chunk done
        if (tid == 0) {
            while (__hip_atomic_load(&cF[g], __ATOMIC_ACQUIRE,
                                     __HIP_MEMORY_SCOPE_AGENT) < 32)
                __builtin_amdgcn_s_sleep(2);
        }
        __syncthreads();

        // depth-4 register prefetch of G1 (slots 0..3)
        float G0[8], G1[8], G2[8], G3[8];
#pragma unroll
        for (int tl = 0; tl < 4; ++tl) {
            G0[tl * 2 + 0] = G1r[(size_t)0 * (BATCH * FOURH) + goff0 + tl * H];
            G0[tl * 2 + 1] = G1r[(size_t)0 * (BATCH * FOURH) + goff1 + tl * H];
            G1[tl * 2 + 0] = G1r[(size_t)1 * (BATCH * FOURH) + goff0 + tl * H];
            G1[tl * 2 + 1] = G1r[(size_t)1 * (BATCH * FOURH) + goff1 + tl * H];
            G2[tl * 2 + 0] = G1r[(size_t)2 * (BATCH * FOURH) + goff0 + tl * H];
            G2[tl * 2 + 1] = G1r[(size_t)2 * (BATCH * FOURH) + goff1 + tl * H];
            G3[tl * 2 + 0] = G1r[(size_t)3 * (BATCH * FOURH) + goff0 + tl * H];
            G3[tl * 2 + 1] = G1r[(size_t)3 * (BATCH * FOURH) + goff1 + tl * H];
        }

#define C_STEP(S, PB, GR)                                                         \
    {                                                                             \
        half8 Afr[4];                                                             \
        _Pragma("unroll")                                                         \
        for (int kf = 0; kf < 4; ++kf)                                            \
            Afr[kf] = *(const half8*)&hbuf[PB][ab][kf * 32 + q * 8];              \
        f32x4 acc[4];                                                             \
        _Pragma("unroll")                                                         \
        for (int tl = 0; tl < 4; ++tl) {                                          \
            acc[tl][0] = GR[tl * 2 + 0]; acc[tl][1] = GR[tl * 2 + 1];             \
            acc[tl][2] = 0.f;            acc[tl][3] = 0.f;                        \
        }                                                                         \
        {                                                                         \
            const float* gp = G1r + (size_t)(((S) + 4) & (RG - 1)) * (BATCH * FOURH); \
            _Pragma("unroll")                                                     \
            for (int tl = 0; tl < 4; ++tl) {                                      \
                GR[tl * 2 + 0] = gp[goff0 + tl * H];                              \
                GR[tl * 2 + 1] = gp[goff1 + tl * H];                              \
            }                                                                     \
        }                                                                         \
        _Pragma("unroll")                                                         \
        for (int kf = 0; kf < 4; ++kf)                                            \
            _Pragma("unroll")                                                     \
            for (int tl = 0; tl < 4; ++tl)                                        \
                acc[tl] = __builtin_amdgcn_mfma_f32_16x16x32_f16(Afr[kf], Bf[tl][kf], acc[tl], 0, 0, 0); \
        {                                                                         \
            float ig = sigmoid_f(acc[0][0]);                                      \
            float fg = sigmoid_f(acc[1][0]);                                      \
            float gg = tanh_f(acc[2][0]);                                         \
            float og = sigmoid_f(acc[3][0]);                                      \
            c0 = fmaf(fg, c0, ig * gg);                                           \
            h0 = og * tanh_f(c0);                                                 \
            float ig1 = sigmoid_f(acc[0][1]);                                     \
            float fg1 = sigmoid_f(acc[1][1]);                                     \
            float gg1 = tanh_f(acc[2][1]);                                        \
            float og1 = sigmoid_f(acc[3][1]);                                     \
            c1 = fmaf(fg1, c1, ig1 * gg1);                                        \
            h1v = og1 * tanh_f(c1);                                               \
        }                                                                         \
        hbuf[PB ^ 1][b0][u]     = (_Float16)h0;                                   \
        hbuf[PB ^ 1][b0 + 1][u] = (_Float16)h1v;                                  \
        houtb[(S) & 7][b0][u]     = h0;                                           \
        houtb[(S) & 7][b0 + 1][u] = h1v;                                          \
        LDS_BARRIER();                                                            \
    }

        for (int s4 = 0; s4 < TC; s4 += 4) {
            if ((s4 & 15) == 0 && s4) {
                if (tid == 0) {
                    int tgt = (s4 + 20 + 31) & ~31;   // covers prefetch t+4 this block
                    if (tgt > TC) tgt = TC;
                    while (__hip_atomic_load(&cF[g], __ATOMIC_ACQUIRE,
                                             __HIP_MEMORY_SCOPE_AGENT) < tgt)
                        __builtin_amdgcn_s_sleep(2);
                }
                __syncthreads();
            }
            C_STEP(s4 + 0, 0, G0)
            C_STEP(s4 + 1, 1, G1)
            C_STEP(s4 + 2, 0, G2)
            C_STEP(s4 + 3, 1, G3)
            if ((s4 & 7) == 4) {
                int sbase = s4 - 4;
#pragma unroll
                for (int k = 0; k < 4; ++k) {
                    int idx = k * 512 + tid;
                    int u4 = idx & 31;
                    int si = (idx >> 5) & 7;
                    int bi = idx >> 8;
                    float4 v = *(const float4*)&houtb[si][bi][u4 * 4];
                    float* dst = houtBase + (size_t)bi * SEQ * H
                               + (size_t)(sbase + si) * H + u4 * 4;
                    *(float4*)dst = v;
                }
                LDS_BARRIER();
            }
            if ((s4 & 15) == 12) {
                if (tid == 0)
                    __hip_atomic_store(&consF[g], s4 + 4, __ATOMIC_RELEASE,
                                       __HIP_MEMORY_SCOPE_AGENT);
            }
        }
#undef C_STEP
    } else {
        // ================= stage C: layer-1 input projection =================
        const int g = blockIdx.x - 16;

        half8 Bf[4][4];   // Wih1 fragments
#pragma unroll
        for (int tl = 0; tl < 4; ++tl)
#pragma unroll
            for (int kf = 0; kf < 4; ++kf) {
                const float* wp = Wih1 + (size_t)(tl * 128 + u) * H + kf * 32 + q * 8;
                float4 v0 = *(const float4*)wp;
                float4 v1 = *(const float4*)(wp + 4);
                half8 b;
                b[0] = (_Float16)v0.x; b[1] = (_Float16)v0.y;
                b[2] = (_Float16)v0.z; b[3] = (_Float16)v0.w;
                b[4] = (_Float16)v1.x; b[5] = (_Float16)v1.y;
                b[6] = (_Float16)v1.z; b[7] = (_Float16)v1.w;
                Bf[tl][kf] = b;
            }

        float bv[4];
#pragma unroll
        for (int tl = 0; tl < 4; ++tl) bv[tl] = b1[tl * 128 + u];

        const int liB = li & 7;      // A-row -> local batch (no dup: 16 rows = 2 steps x 8 batches)
        const int dtl = li >> 3;     // A-row -> step offset
        const int qd  = q >> 1;      // D-row -> step offset
        const int qb  = (q & 1) * 4; // D-row -> batch base

        for (int c = 0; c < TC; c += CCH) {
            if (tid == 0) {
                while (__hip_atomic_load(&prodF[g], __ATOMIC_ACQUIRE,
                                         __HIP_MEMORY_SCOPE_AGENT) < c + CCH)
                    __builtin_amdgcn_s_sleep(2);
                if (c >= RG) {
                    while (__hip_atomic_load(&consF[g], __ATOMIC_ACQUIRE,
                                             __HIP_MEMORY_SCOPE_AGENT) < c + CCH - RG)
                        __builtin_amdgcn_s_sleep(2);
                }
            }
            __syncthreads();
#pragma unroll 2
            for (int rt = 0; rt < 16; ++rt) {
                const _Float16* ap = h1p
                    + ((size_t)(((c + 2 * rt) & (RH - 1)) + dtl)) * (BATCH * H)
                    + (size_t)(8 * g + liB) * H + q * 8;
                half8 Af[4];
#pragma unroll
                for (int kf = 0; kf < 4; ++kf)
                    Af[kf] = *(const half8*)(ap + kf * 32);
                f32x4 acc[4];
#pragma unroll
                for (int tl = 0; tl < 4; ++tl) {
                    acc[tl][0] = bv[tl]; acc[tl][1] = bv[tl];
                    acc[tl][2] = bv[tl]; acc[tl][3] = bv[tl];
                }
#pragma unroll
                for (int kf = 0; kf < 4; ++kf)
#pragma unroll
                    for (int tl = 0; tl < 4; ++tl)
                        acc[tl] = __builtin_amdgcn_mfma_f32_16x16x32_f16(Af[kf], Bf[tl][kf], acc[tl], 0, 0, 0);
                float* op = G1r
                    + ((size_t)((c + 2 * rt) & (RG - 1)) + qd) * (BATCH * FOURH)
                    + (size_t)(8 * g + qb) * FOURH + u;
#pragma unroll
                for (int tl = 0; tl < 4; ++tl)
#pragma unroll
                    for (int i = 0; i < 4; ++i)
                        op[(size_t)i * FOURH + tl * H] = acc[tl][i];
            }
            __threadfence();
            __syncthreads();
            if (tid == 0)
                __hip_atomic_store(&cF[g], c + CCH, __ATOMIC_RELEASE,
                                   __HIP_MEMORY_SCOPE_AGENT);
        }
    }
}

// ---------------- launch ----------------
extern "C" void kernel_launch(void* const* d_in, const int* in_sizes, int n_in,
                              void* d_out, int out_size, void* d_ws, size_t ws_size,
                              hipStream_t stream) {
    const float* x    = (const float*)d_in[0];
    const float* Wih0 = (const float*)d_in[1];
    const float* Whh0 = (const float*)d_in[2];
    const float* bih0 = (const float*)d_in[3];
    const float* bhh0 = (const float*)d_in[4];
    const float* Wih1 = (const float*)d_in[5];
    const float* Whh1 = (const float*)d_in[6];
    const float* bih1 = (const float*)d_in[7];
    const float* bhh1 = (const float*)d_in[8];
    float* out = (float*)d_out;

    char* ws = (char*)d_ws;
    size_t off = 0;
    auto carve = [&](size_t bytes) -> char* {
        char* p = ws + off;
        off += (bytes + 255) & ~(size_t)255;
        return p;
    };

    float*     Wt0   = (float*)carve(256 * 512 * 4);
    float*     b0v   = (float*)carve(512 * 4);
    float*     b1v   = (float*)carve(512 * 4);
    _Float16*  h1p   = (_Float16*)carve((size_t)RH * BATCH * H * 2);     // 16.78 MB ring
    int*       flags = (int*)carve(24 * 4);
    float*     g1r   = (float*)carve((size_t)RG * BATCH * FOURH * 4);    // 16.78 MB ring
    // +16 KB slack: depth-4 prefetch reads up to 4 rows past the end (dead data)
    float*     gbuf  = (float*)carve((size_t)BATCH * SEQ * FOURH * 4 + 16384);

    prep_kernel<<<517, 256, 0, stream>>>(Wih0, bih0, bhh0, bih1, bhh1, Wt0, b0v, b1v, flags);

    // layer-0 input GEMM over the full sequence: [64*2048,256] @ [256,512]
    dim3 ggrid(FOURH / BN, (BATCH * SEQ) / BM);
    gemm_bias_kernel<<<ggrid, 256, 0, stream>>>(x, 256, SEQ, 0, Wt0, b0v, gbuf, 256, 11);

    // fused pipelined 3-stage scan
    lstm_fused_kernel<<<24, 512, 0, stream>>>(gbuf, Whh0, Wih1, Whh1, b1v,
                                              h1p, g1r, out, flags);
}

// Round 3
// 2070.682 us; speedup vs baseline: 1.2157x; 1.2157x over previous
//
#include <hip/hip_runtime.h>
#include <hip/hip_bf16.h>

#define H 128
#define FOURH 512
#define BATCH 64
#define SEQ 2048
#define TC SEQ
#define NCHUNK 128          // 2048 / 16 steps per gemm chunk
#define NGEMMB 224          // gemm worker blocks (blocks 16..239)

typedef _Float16 half8 __attribute__((ext_vector_type(8)));
typedef float f32x4 __attribute__((ext_vector_type(4)));

// ---------------- prep: transpose Wih0 -> [K][512], sum biases, zero flags ----
__global__ void prep_kernel(const float* __restrict__ Wih0,
                            const float* __restrict__ bih0, const float* __restrict__ bhh0,
                            const float* __restrict__ bih1, const float* __restrict__ bhh1,
                            float* __restrict__ Wt0,
                            float* __restrict__ b0, float* __restrict__ b1,
                            int* __restrict__ flags) {
    int id = blockIdx.x * 256 + threadIdx.x;
    const int N0 = 256 * 512;
    if (id < N0) {
        int k = id >> 9, n = id & 511;
        Wt0[id] = Wih0[n * 256 + k];
    } else if (id < N0 + 512) {
        int i = id - N0;
        b0[i] = bih0[i] + bhh0[i];
    } else if (id < N0 + 1024) {
        int i = id - (N0 + 512);
        b1[i] = bih1[i] + bhh1[i];
    } else if (id < N0 + 1024 + 8 + NCHUNK) {
        flags[id - (N0 + 1024)] = 0;
    }
}

// ---------------- fused persistent kernel ----------------
__device__ __forceinline__ float sigmoid_f(float x) {
    return __builtin_amdgcn_rcpf(1.f + __expf(-x));
}
__device__ __forceinline__ float tanh_f(float x) {
    return 1.f - 2.f * __builtin_amdgcn_rcpf(__expf(2.f * x) + 1.f);
}

// Light barrier: LDS handoff only. Global loads/stores stay in flight across it.
#define LDS_BARRIER()                                                \
    do {                                                             \
        asm volatile("s_waitcnt lgkmcnt(0)" ::: "memory");           \
        __builtin_amdgcn_s_barrier();                                \
        __builtin_amdgcn_sched_barrier(0);                           \
    } while (0)

#define BM 128
#define BN 128
#define BK 32

// 240 blocks x 512 threads:
//   blocks 0-7   producer: layer-0 scan over batches 8g..8g+7, gated on gemm
//                chunkDone (16-step granularity), publishes prodF every 32.
//   blocks 8-15  consumer: layer-1 scan (input GEMM fused in-step), lags
//                producer >=64 steps, writes out directly per step.
//   blocks 16-239 gemm workers: G[b][t][512] = x@Wih0^T + b0 in t-ordered
//                16-step chunks (32 sub-blocks/chunk), release chunkDone[c].
// Workers wait on nothing; producer waits only on workers; consumer only on
// producer -> no cycles. All math bit-identical to the R1 kernel.
__global__ __launch_bounds__(512, 2) void lstm_fused_kernel(
    const float* __restrict__ x,      // [64][T][256]
    const float* __restrict__ Wt0,    // [256][512] transposed Wih0
    const float* __restrict__ b0sum,  // [512] summed layer-0 biases
    float* __restrict__ G,            // [64][T][512] layer-0 gate pre-activations
    const float* __restrict__ Whh0,   // [512][128]
    const float* __restrict__ Wih1,   // [512][128]
    const float* __restrict__ Whh1,   // [512][128]
    const float* __restrict__ b1,     // [512] summed layer-1 biases
    _Float16* __restrict__ h1p,       // [T][64][128] fp16 layer-0 hidden
    float* __restrict__ out,          // [64][T][128] fp32 layer-1 hidden
    int* __restrict__ flags)          // [8] prodF + [128] chunkDone
{
    const int tid = threadIdx.x;

    int* prodF     = flags;
    int* chunkDone = flags + 8;

    __shared__ _Float16 hbuf[2][8][136];   // scan recurrent h, fp16, dbuf
    __shared__ float As[BK][BM + 4];       // gemm staging
    __shared__ float Bs[BK][BN];

    if (blockIdx.x >= 16) {
        // ================= gemm workers: layer-0 input GEMM =================
        const int j   = blockIdx.x - 16;    // 0..223
        const int sub = j & 31;             // sub-block within chunk
        const int cls = j >> 5;             // chunk class 0..6
        const int by  = sub >> 2;           // row-block (128 of 1024 chunk rows)
        const int bx  = sub & 3;            // col-block (128 of 512)
        const int n0  = bx * BN;
        const int tm  = tid >> 5;           // 0..15
        const int tn  = tid & 31;           // 0..31

        int ar[2], aq[2], bkk[2], bq[2];
#pragma unroll
        for (int l = 0; l < 2; ++l) {
            int fidx = tid + l * 512;
            ar[l] = fidx >> 3; aq[l] = fidx & 7;      // As: row 0..127, k-quad 0..7
            bkk[l] = fidx >> 5; bq[l] = fidx & 31;    // Bs: k 0..31, col-quad 0..31
        }
        float4 bv = *(const float4*)&b0sum[n0 + tn * 4];

        for (int c = cls; c < NCHUNK; c += 7) {
            const float* aptr[2];
#pragma unroll
            for (int l = 0; l < 2; ++l) {
                int rl = by * BM + ar[l];             // chunk-local row
                int b = rl >> 4;
                int t = c * 16 + (rl & 15);
                aptr[l] = x + ((size_t)b * SEQ + t) * 256 + aq[l] * 4;
            }
            float acc[2][4][4];
#pragma unroll
            for (int rh = 0; rh < 2; ++rh)
#pragma unroll
                for (int i = 0; i < 4; ++i)
#pragma unroll
                    for (int jj = 0; jj < 4; ++jj) acc[rh][i][jj] = 0.f;

            for (int k0 = 0; k0 < 256; k0 += BK) {
                __syncthreads();
#pragma unroll
                for (int l = 0; l < 2; ++l) {
                    float4 v = *(const float4*)(aptr[l] + k0);
                    As[aq[l] * 4 + 0][ar[l]] = v.x;
                    As[aq[l] * 4 + 1][ar[l]] = v.y;
                    As[aq[l] * 4 + 2][ar[l]] = v.z;
                    As[aq[l] * 4 + 3][ar[l]] = v.w;
                }
#pragma unroll
                for (int l = 0; l < 2; ++l) {
                    float4 v = *(const float4*)(Wt0 + (size_t)(k0 + bkk[l]) * FOURH + n0 + bq[l] * 4);
                    *(float4*)&Bs[bkk[l]][bq[l] * 4] = v;
                }
                __syncthreads();
#pragma unroll
                for (int kk = 0; kk < BK; ++kk) {
                    float a[8], bb[4];
                    *(float4*)&a[0] = *(const float4*)&As[kk][tm * 4];
                    *(float4*)&a[4] = *(const float4*)&As[kk][64 + tm * 4];
                    *(float4*)&bb[0] = *(const float4*)&Bs[kk][tn * 4];
#pragma unroll
                    for (int rh = 0; rh < 2; ++rh)
#pragma unroll
                        for (int i = 0; i < 4; ++i)
#pragma unroll
                            for (int jj = 0; jj < 4; ++jj)
                                acc[rh][i][jj] = fmaf(a[rh * 4 + i], bb[jj], acc[rh][i][jj]);
                }
            }
#pragma unroll
            for (int rh = 0; rh < 2; ++rh)
#pragma unroll
                for (int i = 0; i < 4; ++i) {
                    int rl = by * BM + rh * 64 + tm * 4 + i;
                    int b = rl >> 4;
                    int t = c * 16 + (rl & 15);
                    float* gp = G + ((size_t)b * SEQ + t) * FOURH + n0 + tn * 4;
                    float4 o = make_float4(acc[rh][i][0] + bv.x, acc[rh][i][1] + bv.y,
                                           acc[rh][i][2] + bv.z, acc[rh][i][3] + bv.w);
                    *(float4*)gp = o;
                }
            __syncthreads();                 // drains vmcnt: all stores at L2
            if (tid == 0) {
                __threadfence();             // wbl2: visible cross-XCD
                __hip_atomic_fetch_add(&chunkDone[c], 1, __ATOMIC_RELEASE,
                                       __HIP_MEMORY_SCOPE_AGENT);
            }
        }
        return;
    }

    // ================= scan blocks =================
    const int w  = tid >> 6;
    const int l  = tid & 63;
    const int li = l & 15;
    const int q  = l >> 4;
    const int u  = 16 * w + li;                 // owned hidden unit (C col)
    const int b0 = q * 2;                       // local batch for C-row r=0
    const int ab = ((li >> 2) * 2) + (li & 1);  // A-row -> local batch (dup map)

#define WAIT_FLAG(ptr, tgtv)                                                   \
    do {                                                                       \
        if (tid == 0) {                                                        \
            while (__hip_atomic_load((ptr), __ATOMIC_RELAXED,                  \
                                     __HIP_MEMORY_SCOPE_AGENT) < (tgtv))       \
                __builtin_amdgcn_s_sleep(4);                                   \
            (void)__hip_atomic_load((ptr), __ATOMIC_ACQUIRE,                   \
                                    __HIP_MEMORY_SCOPE_AGENT);                 \
        }                                                                      \
        __syncthreads();                                                       \
    } while (0)

    if (blockIdx.x < 8) {
        // ================= producer: layer 0 =================
        const int g = blockIdx.x;

        half8 Bf[4][4];
#pragma unroll
        for (int tl = 0; tl < 4; ++tl)
#pragma unroll
            for (int kf = 0; kf < 4; ++kf) {
                const float* wp = Whh0 + (size_t)(tl * 128 + u) * H + kf * 32 + q * 8;
                float4 v0 = *(const float4*)wp;
                float4 v1 = *(const float4*)(wp + 4);
                half8 b;
                b[0] = (_Float16)v0.x; b[1] = (_Float16)v0.y;
                b[2] = (_Float16)v0.z; b[3] = (_Float16)v0.w;
                b[4] = (_Float16)v1.x; b[5] = (_Float16)v1.y;
                b[6] = (_Float16)v1.z; b[7] = (_Float16)v1.w;
                Bf[tl][kf] = b;
            }

        float c0 = 0.f, c1 = 0.f, h0 = 0.f, h1v = 0.f;
        hbuf[0][b0][u]     = (_Float16)0.f;
        hbuf[0][b0 + 1][u] = (_Float16)0.f;

        const float* gb = G + (size_t)(8 * g) * TC * FOURH;
        const int voff0 = b0 * TC * FOURH + u;
        const int voff1 = (b0 + 1) * TC * FOURH + u;

        WAIT_FLAG(&chunkDone[0], 32);     // chunk 0 ready (also orders hbuf init)

        // depth-4 register prefetch of G (static register sets; self-reload)
        float G0[8], G1[8], G2[8], G3[8];
        const float* gld = gb;
#pragma unroll
        for (int tl = 0; tl < 4; ++tl) {
            G0[tl * 2 + 0] = gld[voff0 + tl * H];
            G0[tl * 2 + 1] = gld[voff1 + tl * H];
        }
        gld += FOURH;
#pragma unroll
        for (int tl = 0; tl < 4; ++tl) {
            G1[tl * 2 + 0] = gld[voff0 + tl * H];
            G1[tl * 2 + 1] = gld[voff1 + tl * H];
        }
        gld += FOURH;
#pragma unroll
        for (int tl = 0; tl < 4; ++tl) {
            G2[tl * 2 + 0] = gld[voff0 + tl * H];
            G2[tl * 2 + 1] = gld[voff1 + tl * H];
        }
        gld += FOURH;
#pragma unroll
        for (int tl = 0; tl < 4; ++tl) {
            G3[tl * 2 + 0] = gld[voff0 + tl * H];
            G3[tl * 2 + 1] = gld[voff1 + tl * H];
        }
        gld += FOURH;   // now points at t=4

        _Float16* php = h1p + (size_t)(8 * g + b0) * H + u;   // +step*8192

#define P_STEP(PB, GR)                                                            \
    {                                                                             \
        half8 Afr[4];                                                             \
        _Pragma("unroll")                                                         \
        for (int kf = 0; kf < 4; ++kf)                                            \
            Afr[kf] = *(const half8*)&hbuf[PB][ab][kf * 32 + q * 8];              \
        f32x4 acc[4];                                                             \
        _Pragma("unroll")                                                         \
        for (int tl = 0; tl < 4; ++tl) {                                          \
            acc[tl][0] = GR[tl * 2 + 0]; acc[tl][1] = GR[tl * 2 + 1];             \
            acc[tl][2] = 0.f;            acc[tl][3] = 0.f;                        \
        }                                                                         \
        _Pragma("unroll")                                                         \
        for (int tl = 0; tl < 4; ++tl) {                                          \
            GR[tl * 2 + 0] = gld[voff0 + tl * H];                                 \
            GR[tl * 2 + 1] = gld[voff1 + tl * H];                                 \
        }                                                                         \
        gld += FOURH;                                                             \
        _Pragma("unroll")                                                         \
        for (int kf = 0; kf < 4; ++kf)                                            \
            _Pragma("unroll")                                                     \
            for (int tl = 0; tl < 4; ++tl)                                        \
                acc[tl] = __builtin_amdgcn_mfma_f32_16x16x32_f16(Afr[kf], Bf[tl][kf], acc[tl], 0, 0, 0); \
        {                                                                         \
            float ig = sigmoid_f(acc[0][0]);                                      \
            float fg = sigmoid_f(acc[1][0]);                                      \
            float gg = tanh_f(acc[2][0]);                                         \
            float og = sigmoid_f(acc[3][0]);                                      \
            c0 = fmaf(fg, c0, ig * gg);                                           \
            h0 = og * tanh_f(c0);                                                 \
            float ig1 = sigmoid_f(acc[0][1]);                                     \
            float fg1 = sigmoid_f(acc[1][1]);                                     \
            float gg1 = tanh_f(acc[2][1]);                                        \
            float og1 = sigmoid_f(acc[3][1]);                                     \
            c1 = fmaf(fg1, c1, ig1 * gg1);                                        \
            h1v = og1 * tanh_f(c1);                                               \
        }                                                                         \
        hbuf[PB ^ 1][b0][u]     = (_Float16)h0;                                   \
        hbuf[PB ^ 1][b0 + 1][u] = (_Float16)h1v;                                  \
        php[0]   = (_Float16)h0;                                                  \
        php[128] = (_Float16)h1v;                                                 \
        php += BATCH * H;                                                         \
        LDS_BARRIER();                                                            \
    }

        for (int s4 = 0; s4 < TC; s4 += 4) {
            if ((s4 & 15) == 0) {
                int k = (s4 >> 4) + 1;               // next chunk (prefetch spills into it)
                if (k > NCHUNK - 1) k = NCHUNK - 1;
                WAIT_FLAG(&chunkDone[k], 32);
            }
            P_STEP(0, G0)
            P_STEP(1, G1)
            P_STEP(0, G2)
            P_STEP(1, G3)
            if ((s4 & 31) == 28) {
                __threadfence();            // drain + make h1p stores device-visible
                __syncthreads();            // all waves fenced before flag
                if (tid == 0)
                    __hip_atomic_store(&prodF[g], s4 + 4, __ATOMIC_RELEASE,
                                       __HIP_MEMORY_SCOPE_AGENT);
            }
        }
#undef P_STEP
    } else {
        // ================= consumer: layer 1 =================
        const int g = blockIdx.x - 8;

        // Bf[tl][kf]: kf<4 from Wih1 (applies to h1_t), kf>=4 from Whh1 (h2_{t-1})
        half8 Bf[4][8];
#pragma unroll
        for (int tl = 0; tl < 4; ++tl)
#pragma unroll
            for (int kf = 0; kf < 8; ++kf) {
                const float* base = (kf < 4) ? Wih1 : Whh1;
                int kk = (kf & 3) * 32 + q * 8;
                const float* wp = base + (size_t)(tl * 128 + u) * H + kk;
                float4 v0 = *(const float4*)wp;
                float4 v1 = *(const float4*)(wp + 4);
                half8 b;
                b[0] = (_Float16)v0.x; b[1] = (_Float16)v0.y;
                b[2] = (_Float16)v0.z; b[3] = (_Float16)v0.w;
                b[4] = (_Float16)v1.x; b[5] = (_Float16)v1.y;
                b[6] = (_Float16)v1.z; b[7] = (_Float16)v1.w;
                Bf[tl][kf] = b;
            }

        float bv[4];
#pragma unroll
        for (int tl = 0; tl < 4; ++tl) bv[tl] = b1[tl * 128 + u];

        float c0 = 0.f, c1 = 0.f, h0, h1v;
        hbuf[0][b0][u]     = (_Float16)0.f;
        hbuf[0][b0 + 1][u] = (_Float16)0.f;

        const _Float16* h1pG = h1p + (size_t)(8 * g + ab) * H + q * 8;  // +t*8192
        float* op0 = out + (size_t)(8 * g + b0) * SEQ * H + u;          // +step*H
        float* op1 = out + (size_t)(8 * g + b0 + 1) * SEQ * H + u;

        // initial acquire: 64-step producer lead (also orders hbuf init)
        WAIT_FLAG(&prodF[g], 64);

        // depth-2 register prefetch of h1 fragments (static sets, self-reload)
        half8 Af0[4], Af1[4];
#pragma unroll
        for (int kf = 0; kf < 4; ++kf)
            Af0[kf] = *(const half8*)(h1pG + kf * 32);                         // t=0
        {
            const _Float16* hp = h1pG + (size_t)(BATCH * H);                   // t=1
#pragma unroll
            for (int kf = 0; kf < 4; ++kf)
                Af1[kf] = *(const half8*)(hp + kf * 32);
        }

#define C_STEP(S, PB, AfU)                                                        \
    {                                                                             \
        half8 Ah[4];                                                              \
        _Pragma("unroll")                                                         \
        for (int kf = 0; kf < 4; ++kf)                                            \
            Ah[kf] = *(const half8*)&hbuf[PB][ab][kf * 32 + q * 8];               \
        f32x4 acc[4];                                                             \
        _Pragma("unroll")                                                         \
        for (int tl = 0; tl < 4; ++tl) {                                          \
            acc[tl][0] = bv[tl]; acc[tl][1] = bv[tl];                             \
            acc[tl][2] = bv[tl]; acc[tl][3] = bv[tl];                             \
        }                                                                         \
        _Pragma("unroll")                                                         \
        for (int kf = 0; kf < 4; ++kf)                                            \
            _Pragma("unroll")                                                     \
            for (int tl = 0; tl < 4; ++tl)                                        \
                acc[tl] = __builtin_amdgcn_mfma_f32_16x16x32_f16(AfU[kf], Bf[tl][kf], acc[tl], 0, 0, 0); \
        {                                                                         \
            int sn = (S) + 2; if (sn > TC - 1) sn = TC - 1;                       \
            const _Float16* hp = h1pG + (size_t)sn * (BATCH * H);                 \
            _Pragma("unroll")                                                     \
            for (int kf = 0; kf < 4; ++kf)                                        \
                AfU[kf] = *(const half8*)(hp + kf * 32);                          \
        }                                                                         \
        _Pragma("unroll")                                                         \
        for (int kf = 0; kf < 4; ++kf)                                            \
            _Pragma("unroll")                                                     \
            for (int tl = 0; tl < 4; ++tl)                                        \
                acc[tl] = __builtin_amdgcn_mfma_f32_16x16x32_f16(Ah[kf], Bf[tl][kf + 4], acc[tl], 0, 0, 0); \
        {                                                                         \
            float ig = sigmoid_f(acc[0][0]);                                      \
            float fg = sigmoid_f(acc[1][0]);                                      \
            float gg = tanh_f(acc[2][0]);                                         \
            float og = sigmoid_f(acc[3][0]);                                      \
            c0 = fmaf(fg, c0, ig * gg);                                           \
            h0 = og * tanh_f(c0);                                                 \
            float ig1 = sigmoid_f(acc[0][1]);                                     \
            float fg1 = sigmoid_f(acc[1][1]);                                     \
            float gg1 = tanh_f(acc[2][1]);                                        \
            float og1 = sigmoid_f(acc[3][1]);                                     \
            c1 = fmaf(fg1, c1, ig1 * gg1);                                        \
            h1v = og1 * tanh_f(c1);                                               \
        }                                                                         \
        hbuf[PB ^ 1][b0][u]     = (_Float16)h0;                                   \
        hbuf[PB ^ 1][b0 + 1][u] = (_Float16)h1v;                                  \
        op0[0] = h0;                                                              \
        op1[0] = h1v;                                                             \
        op0 += H; op1 += H;                                                       \
        LDS_BARRIER();                                                            \
    }

        for (int s4 = 0; s4 < TC; s4 += 4) {
            if (s4 && (s4 & 31) == 0) {
                int tgt = s4 + 64; if (tgt > TC) tgt = TC;
                WAIT_FLAG(&prodF[g], tgt);
            }
            C_STEP(s4 + 0, 0, Af0)
            C_STEP(s4 + 1, 1, Af1)
            C_STEP(s4 + 2, 0, Af0)
            C_STEP(s4 + 3, 1, Af1)
        }
#undef C_STEP
    }
#undef WAIT_FLAG
}

// ---------------- launch ----------------
extern "C" void kernel_launch(void* const* d_in, const int* in_sizes, int n_in,
                              void* d_out, int out_size, void* d_ws, size_t ws_size,
                              hipStream_t stream) {
    const float* x    = (const float*)d_in[0];
    const float* Wih0 = (const float*)d_in[1];
    const float* Whh0 = (const float*)d_in[2];
    const float* bih0 = (const float*)d_in[3];
    const float* bhh0 = (const float*)d_in[4];
    const float* Wih1 = (const float*)d_in[5];
    const float* Whh1 = (const float*)d_in[6];
    const float* bih1 = (const float*)d_in[7];
    const float* bhh1 = (const float*)d_in[8];
    float* out = (float*)d_out;

    char* ws = (char*)d_ws;
    size_t off = 0;
    auto carve = [&](size_t bytes) -> char* {
        char* p = ws + off;
        off += (bytes + 255) & ~(size_t)255;
        return p;
    };

    float*     Wt0   = (float*)carve(256 * 512 * 4);
    float*     b0v   = (float*)carve(512 * 4);
    float*     b1v   = (float*)carve(512 * 4);
    _Float16*  h1p   = (_Float16*)carve((size_t)SEQ * BATCH * H * 2);
    int*       flags = (int*)carve((8 + NCHUNK) * 4);
    // +16 KB slack: depth-4 prefetch reads up to 4 rows past the end (dead data)
    float*     gbuf  = (float*)carve((size_t)BATCH * SEQ * FOURH * 4 + 16384);

    prep_kernel<<<517, 256, 0, stream>>>(Wih0, bih0, bhh0, bih1, bhh1, Wt0, b0v, b1v, flags);

    // single persistent kernel: gemm workers + 2-layer pipelined scan
    lstm_fused_kernel<<<240, 512, 0, stream>>>(x, Wt0, b0v, gbuf,
                                               Whh0, Wih1, Whh1, b1v,
                                               h1p, out, flags);
}